// Round 6
// baseline (82.369 us; speedup 1.0000x reference)
//
#include <hip/hip_runtime.h>
#include <math.h>

#define D 256
#define NRULES 1024
#define TPB 8     // tokens per pass
#define KMAX 16   // bucket stride; slot>=KMAX spills (P~1e-6 total at Poisson(2))

// ---------------- prep: histogram buckets + compact unit worklist ----------------
__global__ void prep_kernel(const int* __restrict__ token_ids,
                            const int* __restrict__ token_rules,
                            int ntok,
                            int* __restrict__ counts,        // [NRULES] pre-zeroed
                            int* __restrict__ bucket,        // [NRULES*KMAX]
                            int* __restrict__ rule_of_token, // [ntok]
                            int* __restrict__ worklist,      // [4*(NRULES+spill)]
                            int* __restrict__ nunits) {      // [1] pre-zeroed
    const int i = blockIdx.x * blockDim.x + threadIdx.x;
    if (i >= ntok) return;
    const int r = token_rules[token_ids[i]];
    rule_of_token[i] = r;
    const int slot = atomicAdd(&counts[r], 1);
    if (slot < KMAX) {
        bucket[r * KMAX + slot] = i;
        if (slot == 0) {  // first token of rule r -> emit its 4 quarter-units
            const int w = atomicAdd(nunits, 4);
            #pragma unroll
            for (int q = 0; q < 4; ++q) worklist[w + q] = (r << 2) | q;
        }
    } else {              // overflow: token-private units (fro2 owned by main unit)
        const int w = atomicAdd(nunits, 4);
        #pragma unroll
        for (int q = 0; q < 4; ++q)
            worklist[w + q] = (int)(0x80000000u | ((unsigned)i << 2) | (unsigned)q);
    }
}

// ---------------- count-templated quarter compute ----------------
template <int CNT>
__device__ __forceinline__ void quarter_compute(
    const float* __restrict__ M, const float (*__restrict__ h_lds)[D],
    int rr, int col, float4* acc, float& sq)
{
    #pragma unroll 8
    for (int i = 0; i < 64; ++i) {
        const int d = (i << 2) + rr;
        const float4 m = *reinterpret_cast<const float4*>(M + (size_t)d * D + col);
        sq = fmaf(m.x, m.x, fmaf(m.y, m.y, fmaf(m.z, m.z, fmaf(m.w, m.w, sq))));
        #pragma unroll
        for (int j = 0; j < CNT; ++j) {
            const float h = h_lds[j][d];  // 4 addrs/wave, x16 broadcast
            acc[j].x = fmaf(h, m.x, acc[j].x);
            acc[j].y = fmaf(h, m.y, acc[j].y);
            acc[j].z = fmaf(h, m.z, acc[j].z);
            acc[j].w = fmaf(h, m.w, acc[j].w);
        }
    }
}

// ---------------- main: one 64-thread wave per (rule, column-quarter) ----------------
// rr = lane>>4 row-subgroup (rows 4i+rr), lane&15 picks 4 cols of the 64-col quarter.
__global__ __launch_bounds__(64) void matvec_kernel(
    const float* __restrict__ hidden,        // [NTOK, D]
    const float* __restrict__ rules,         // [NRULES, D, D]
    const int*   __restrict__ counts,
    const int*   __restrict__ bucket,
    const int*   __restrict__ rule_of_token,
    const int*   __restrict__ worklist,
    const int*   __restrict__ nunits,
    float* __restrict__ fro2buf,             // [NRULES*4] per-quarter sq partials
    float* __restrict__ out)                 // [NTOK, D] unnormalized
{
    if ((int)blockIdx.x >= nunits[0]) return;
    const int e  = worklist[blockIdx.x];
    const int t  = threadIdx.x;
    const int rr = t >> 4;
    const int c4 = (t & 15) << 2;

    __shared__ float h_lds[TPB][D];
    __shared__ int   toks[KMAX];

    int r, q, cnt;
    bool owner;
    if (e < 0) {  // spill unit: single token
        const int tok = (e & 0x7fffffff) >> 2;
        q = e & 3;
        r = rule_of_token[tok];
        cnt = 1;
        owner = false;
        if (t == 0) toks[0] = tok;
    } else {
        r = e >> 2; q = e & 3;
        cnt = min(counts[r], KMAX);
        owner = true;
        if (t < cnt) toks[t] = bucket[r * KMAX + t];
    }
    __syncthreads();

    const int col = (q << 6) + c4;
    const float* __restrict__ M = rules + (size_t)r * D * D;

    for (int base = 0; base < cnt; base += TPB) {
        const int c  = min(cnt - base, TPB);
        const int cr = (c == 1) ? 1 : (c == 2) ? 2 : (c <= 4) ? 4 : 8;

        // stage h rows: thread t loads floats [4t,4t+4) of each token row
        for (int j = 0; j < cr; ++j) {
            float4 v = {0.f, 0.f, 0.f, 0.f};
            if (j < c)
                v = *reinterpret_cast<const float4*>(
                    &hidden[(size_t)toks[base + j] * D + (t << 2)]);
            *reinterpret_cast<float4*>(&h_lds[j][t << 2]) = v;
        }
        __syncthreads();

        float4 acc[TPB];
        #pragma unroll
        for (int j = 0; j < TPB; ++j) acc[j] = float4{0.f, 0.f, 0.f, 0.f};
        float sq = 0.f;

        switch (cr) {
            case 1: quarter_compute<1>(M, h_lds, rr, col, acc, sq); break;
            case 2: quarter_compute<2>(M, h_lds, rr, col, acc, sq); break;
            case 4: quarter_compute<4>(M, h_lds, rr, col, acc, sq); break;
            default: quarter_compute<8>(M, h_lds, rr, col, acc, sq); break;
        }

        // butterfly over the 4 row-subgroups: every lane gets full column sums
        for (int j = 0; j < cr; ++j) {
            #pragma unroll
            for (int mask = 16; mask < 64; mask <<= 1) {
                acc[j].x += __shfl_xor(acc[j].x, mask, 64);
                acc[j].y += __shfl_xor(acc[j].y, mask, 64);
                acc[j].z += __shfl_xor(acc[j].z, mask, 64);
                acc[j].w += __shfl_xor(acc[j].w, mask, 64);
            }
        }

        if (owner && base == 0) {
            float s = sq;
            #pragma unroll
            for (int off = 32; off > 0; off >>= 1)
                s += __shfl_down(s, off, 64);
            if (t == 0) fro2buf[(r << 2) | q] = s;
        }

        // subgroup (j&3) writes token j's quarter (16 lanes x float4 = 64 cols)
        for (int j = 0; j < cr; ++j) {
            if (j < c && rr == (j & 3)) {
                const int tok = toks[base + j];
                *reinterpret_cast<float4*>(&out[(size_t)tok * D + col]) = acc[j];
            }
        }
        __syncthreads();  // protect h_lds before restage
    }
}

// ---------------- epilogue: scale by 1/max(||M||_F, eps) ----------------
__global__ __launch_bounds__(256) void norm_kernel(
    float* __restrict__ out,
    const int* __restrict__ rule_of_token,
    const float* __restrict__ fro2buf,
    int ntok)
{
    const int g   = blockIdx.x * 256 + threadIdx.x;  // one float4 per thread
    const int tok = g >> 6;
    if (tok >= ntok) return;
    const int c4  = (g & 63) << 2;
    const int r   = rule_of_token[tok];
    const float f = fro2buf[r * 4] + fro2buf[r * 4 + 1] +
                    fro2buf[r * 4 + 2] + fro2buf[r * 4 + 3];
    const float inv = 1.0f / fmaxf(sqrtf(f), 1e-12f);
    float4 v = *reinterpret_cast<float4*>(&out[(size_t)tok * D + c4]);
    v.x *= inv; v.y *= inv; v.z *= inv; v.w *= inv;
    *reinterpret_cast<float4*>(&out[(size_t)tok * D + c4]) = v;
}

// ---------------- launcher ----------------
extern "C" void kernel_launch(void* const* d_in, const int* in_sizes, int n_in,
                              void* d_out, int out_size, void* d_ws, size_t ws_size,
                              hipStream_t stream) {
    const float* hidden      = (const float*)d_in[0];
    const int*   token_ids   = (const int*)d_in[1];
    const float* rules       = (const float*)d_in[2];
    const int*   token_rules = (const int*)d_in[3];
    float*       out         = (float*)d_out;

    const int ntok = in_sizes[1];  // B*S

    int* ws            = (int*)d_ws;
    int* counts        = ws;                          // NRULES
    int* nunits        = ws + NRULES;                 // 1 (pad 8)
    int* bucket        = ws + NRULES + 8;             // NRULES*KMAX
    int* rule_of_token = bucket + NRULES * KMAX;      // ntok
    int* worklist      = rule_of_token + ntok;        // up to 4*NRULES + spill
    float* fro2buf     = (float*)(worklist + 4 * NRULES + 1024);  // NRULES*4

    const int max_units = 4 * NRULES + 256;  // spill headroom

    hipMemsetAsync(counts, 0, (NRULES + 8) * sizeof(int), stream);
    prep_kernel<<<(ntok + 255) / 256, 256, 0, stream>>>(
        token_ids, token_rules, ntok, counts, bucket, rule_of_token,
        worklist, nunits);
    matvec_kernel<<<max_units, 64, 0, stream>>>(
        hidden, rules, counts, bucket, rule_of_token, worklist, nunits,
        fro2buf, out);
    norm_kernel<<<(ntok * 64 + 255) / 256, 256, 0, stream>>>(
        out, rule_of_token, fro2buf, ntok);
}

// Round 7
// 73.189 us; speedup vs baseline: 1.1254x; 1.1254x over previous
//
#include <hip/hip_runtime.h>
#include <math.h>

#define D 256
#define NRULES 1024
#define TPB 8     // tokens per pass
#define KMAX 16   // bucket stride; slot>=KMAX spills (P ~ 0 at Poisson(2))
#define NSPILLBLK 64

// ---------------- prep: parallel histogram, no scan ----------------
__global__ void prep_kernel(const int* __restrict__ token_ids,
                            const int* __restrict__ token_rules,
                            int ntok,
                            int* __restrict__ counts,        // [NRULES] pre-zeroed
                            int* __restrict__ bucket,        // [NRULES*KMAX]
                            int* __restrict__ rule_of_token, // [ntok]
                            int* __restrict__ spill,         // [ntok]
                            int* __restrict__ nspill) {      // [1] pre-zeroed
    const int i = blockIdx.x * blockDim.x + threadIdx.x;
    if (i >= ntok) return;
    const int r = token_rules[token_ids[i]];
    rule_of_token[i] = r;
    const int slot = atomicAdd(&counts[r], 1);
    if (slot < KMAX) bucket[r * KMAX + slot] = i;
    else             spill[atomicAdd(nspill, 1)] = i;
}

// ---------------- templated row-range compute ----------------
// NITER iterations over rows; row d = 4*i + rr (local), h index HOFF + d.
template <int CNT>
__device__ __forceinline__ void rows_compute(
    const float* __restrict__ M, const float (*__restrict__ h_lds)[D],
    int niter, int hoff, int rr, int col, float4* acc, float& sq)
{
    #pragma unroll 4
    for (int i = 0; i < niter; ++i) {
        const int dl = (i << 2) + rr;
        const float4 m = *reinterpret_cast<const float4*>(M + (size_t)dl * D + col);
        sq = fmaf(m.x, m.x, fmaf(m.y, m.y, fmaf(m.z, m.z, fmaf(m.w, m.w, sq))));
        #pragma unroll
        for (int j = 0; j < CNT; ++j) {
            const float h = h_lds[j][hoff + dl];  // 4 addrs/wave, x16 broadcast
            acc[j].x = fmaf(h, m.x, acc[j].x);
            acc[j].y = fmaf(h, m.y, acc[j].y);
            acc[j].z = fmaf(h, m.z, acc[j].z);
            acc[j].w = fmaf(h, m.w, acc[j].w);
        }
    }
}

// ---------------- main: block b<2048 -> (rule b>>1, row-half b&1) ----------------
// 256 thr = 4 waves; wave owns 64-col quarter; rr=lane>>4 row subgroup.
// All 4 waves walk the same rows in lockstep -> full 1KB DRAM rows per window.
__global__ __launch_bounds__(256) void matvec_kernel(
    const float* __restrict__ hidden,        // [NTOK, D]
    const float* __restrict__ rules,         // [NRULES, D, D]
    const int*   __restrict__ counts,
    const int*   __restrict__ bucket,
    const int*   __restrict__ rule_of_token,
    const int*   __restrict__ spill,
    const int*   __restrict__ nspill,
    float* __restrict__ fro8,                // [NRULES*8] (half*4+wave) sq partials
    float* __restrict__ pbuf)                // [NTOK*2*D] per-half partial y
{
    const int b    = blockIdx.x;
    const int t    = threadIdx.x;
    const int wave = t >> 6;
    const int lane = t & 63;
    const int rr   = lane >> 4;
    const int col  = (wave << 6) + ((lane & 15) << 2);

    __shared__ float h_lds[TPB][D];
    __shared__ int   toks[KMAX];

    if (b < 2 * NRULES) {
        const int r    = b >> 1;
        const int half = b & 1;
        const int cnt  = min(counts[r], KMAX);
        if (cnt == 0) return;
        if (t < cnt) toks[t] = bucket[r * KMAX + t];
        __syncthreads();

        const float* __restrict__ M = rules + (size_t)r * D * D + (size_t)half * 128 * D;
        const int hoff = half << 7;

        for (int base = 0; base < cnt; base += TPB) {
            const int c  = min(cnt - base, TPB);
            const int cr = (c == 1) ? 1 : (c == 2) ? 2 : (c <= 4) ? 4 : 8;

            #pragma unroll
            for (int j = 0; j < TPB; ++j)
                h_lds[j][t] = (j < c) ? hidden[(size_t)toks[base + j] * D + t] : 0.f;
            __syncthreads();

            float4 acc[TPB];
            #pragma unroll
            for (int j = 0; j < TPB; ++j) acc[j] = float4{0.f, 0.f, 0.f, 0.f};
            float sq = 0.f;

            switch (cr) {
                case 1:  rows_compute<1>(M, h_lds, 32, hoff, rr, col, acc, sq); break;
                case 2:  rows_compute<2>(M, h_lds, 32, hoff, rr, col, acc, sq); break;
                case 4:  rows_compute<4>(M, h_lds, 32, hoff, rr, col, acc, sq); break;
                default: rows_compute<8>(M, h_lds, 32, hoff, rr, col, acc, sq); break;
            }

            if (base == 0) {  // sq identical every pass; write once
                float s = sq;
                #pragma unroll
                for (int off = 32; off > 0; off >>= 1)
                    s += __shfl_down(s, off, 64);
                if (lane == 0) fro8[(r << 3) + (half << 2) + wave] = s;
            }

            // butterfly over the 4 row-subgroups
            for (int j = 0; j < cr; ++j) {
                #pragma unroll
                for (int mask = 16; mask < 64; mask <<= 1) {
                    acc[j].x += __shfl_xor(acc[j].x, mask, 64);
                    acc[j].y += __shfl_xor(acc[j].y, mask, 64);
                    acc[j].z += __shfl_xor(acc[j].z, mask, 64);
                    acc[j].w += __shfl_xor(acc[j].w, mask, 64);
                }
            }

            for (int j = 0; j < cr; ++j) {
                if (j < c && rr == (j & 3)) {
                    const int tok = toks[base + j];
                    *reinterpret_cast<float4*>(
                        &pbuf[((size_t)tok * 2 + half) * D + col]) = acc[j];
                }
            }
            __syncthreads();  // protect h_lds before restage
        }
    } else {
        // spill tail: full 256-row matvec per token; pbuf[half0]=y, pbuf[half1]=0
        const int ns = nspill[0];
        for (int k = b - 2 * NRULES; k < ns; k += NSPILLBLK) {
            const int tok = spill[k];
            const int r   = rule_of_token[tok];
            h_lds[0][t] = hidden[(size_t)tok * D + t];
            __syncthreads();

            float4 acc[1] = {float4{0.f, 0.f, 0.f, 0.f}};
            float sq = 0.f;
            rows_compute<1>(rules + (size_t)r * D * D, h_lds, 64, 0, rr, col, acc, sq);

            #pragma unroll
            for (int mask = 16; mask < 64; mask <<= 1) {
                acc[0].x += __shfl_xor(acc[0].x, mask, 64);
                acc[0].y += __shfl_xor(acc[0].y, mask, 64);
                acc[0].z += __shfl_xor(acc[0].z, mask, 64);
                acc[0].w += __shfl_xor(acc[0].w, mask, 64);
            }
            if (rr == 0) {
                *reinterpret_cast<float4*>(&pbuf[((size_t)tok * 2 + 0) * D + col]) = acc[0];
                *reinterpret_cast<float4*>(&pbuf[((size_t)tok * 2 + 1) * D + col]) =
                    float4{0.f, 0.f, 0.f, 0.f};
            }
            __syncthreads();
        }
    }
}

// ---------------- epilogue: combine halves + normalize ----------------
__global__ __launch_bounds__(256) void norm_kernel(
    const float* __restrict__ pbuf,
    const int*   __restrict__ rule_of_token,
    const float* __restrict__ fro8,
    float* __restrict__ out,
    int ntok)
{
    const int g   = blockIdx.x * 256 + threadIdx.x;  // one float4 per thread
    const int tok = g >> 6;
    if (tok >= ntok) return;
    const int c4  = (g & 63) << 2;
    const int r   = rule_of_token[tok];
    const float* f8 = &fro8[r << 3];
    const float f = ((f8[0] + f8[1]) + (f8[2] + f8[3])) +
                    ((f8[4] + f8[5]) + (f8[6] + f8[7]));
    const float inv = 1.0f / fmaxf(sqrtf(f), 1e-12f);
    const float4 a = *reinterpret_cast<const float4*>(&pbuf[((size_t)tok * 2 + 0) * D + c4]);
    const float4 bb= *reinterpret_cast<const float4*>(&pbuf[((size_t)tok * 2 + 1) * D + c4]);
    float4 v;
    v.x = (a.x + bb.x) * inv; v.y = (a.y + bb.y) * inv;
    v.z = (a.z + bb.z) * inv; v.w = (a.w + bb.w) * inv;
    *reinterpret_cast<float4*>(&out[(size_t)tok * D + c4]) = v;
}

// ---------------- launcher ----------------
extern "C" void kernel_launch(void* const* d_in, const int* in_sizes, int n_in,
                              void* d_out, int out_size, void* d_ws, size_t ws_size,
                              hipStream_t stream) {
    const float* hidden      = (const float*)d_in[0];
    const int*   token_ids   = (const int*)d_in[1];
    const float* rules       = (const float*)d_in[2];
    const int*   token_rules = (const int*)d_in[3];
    float*       out         = (float*)d_out;

    const int ntok = in_sizes[1];  // B*S

    int* ws            = (int*)d_ws;
    int* counts        = ws;                          // NRULES
    int* nspill        = ws + NRULES;                 // 1 (pad 8)
    int* bucket        = ws + NRULES + 8;             // NRULES*KMAX
    int* rule_of_token = bucket + NRULES * KMAX;      // ntok
    int* spill         = rule_of_token + ntok;        // ntok
    float* fro8        = (float*)(spill + ntok);      // NRULES*8
    float* pbuf        = fro8 + NRULES * 8;           // ntok*2*D

    hipMemsetAsync(counts, 0, (NRULES + 8) * sizeof(int), stream);
    prep_kernel<<<(ntok + 255) / 256, 256, 0, stream>>>(
        token_ids, token_rules, ntok, counts, bucket, rule_of_token, spill, nspill);
    matvec_kernel<<<2 * NRULES + NSPILLBLK, 256, 0, stream>>>(
        hidden, rules, counts, bucket, rule_of_token, spill, nspill, fro8, pbuf);
    norm_kernel<<<(ntok * 64 + 255) / 256, 256, 0, stream>>>(
        pbuf, rule_of_token, fro8, out, ntok);
}